// Round 8
// baseline (291.667 us; speedup 1.0000x reference)
//
#include <hip/hip_runtime.h>

#define N_ATOMS 10000
#define N_EDGES 160000
#define N_STRUCT 8
#define D_PAD 48             // max slots per atom; P(Poisson(16) > 48) ~ 2e-7 overall
#define EDW 48               // floats per slot: [0..15]=sh, [16..31]=R, [32..47]=hs
#define N_SLOTS (N_ATOMS * D_PAD)
#define B4 4                 // slots per register batch (12 loads in flight per buffer)
#define PI_F 3.14159265358979323846f

// ---------------- setup ----------------

__global__ void init_kernel(int* __restrict__ cursor, float* __restrict__ accum) {
    int i = blockIdx.x * blockDim.x + threadIdx.x;
    if (i < N_ATOMS) cursor[i] = i * D_PAD;
    if (i < N_STRUCT) accum[i] = 0.f;
}

__global__ void scatter_kernel(const int* __restrict__ receivers, int* __restrict__ cursor,
                               int* __restrict__ perm) {
    int e = blockIdx.x * blockDim.x + threadIdx.x;
    if (e < N_EDGES) perm[e] = atomicAdd(&cursor[receivers[e]], 1);
}

// zero ONLY the pad slots [cnt, ceil4(cnt)) of each atom (all 48 floats, so
// uninitialized workspace bits can never reach the accumulator)
__global__ void pad_kernel(const int* __restrict__ cursor, float* __restrict__ edat) {
    int i = blockIdx.x * blockDim.x + threadIdx.x;
    if (i >= N_ATOMS * 3) return;
    int a = i / 3, j = i % 3;
    int cnt = cursor[a] - a * D_PAD;
    if (cnt > D_PAD) cnt = D_PAD;
    int c4 = (cnt + B4 - 1) / B4 * B4;
    if (c4 > D_PAD) c4 = D_PAD;
    int slot = cnt + j;
    if (slot < c4) {
        float4 z = make_float4(0.f, 0.f, 0.f, 0.f);
        float4* p = (float4*)(edat + (size_t)(a * D_PAD + slot) * EDW);
        #pragma unroll
        for (int k = 0; k < 12; ++k) p[k] = z;
    }
}

__global__ void emb_kernel(const float* __restrict__ embed, const int* __restrict__ species,
                           float* __restrict__ h0) {
    int i = blockIdx.x * blockDim.x + threadIdx.x;
    if (i < N_ATOMS * 16) {
        int a = i >> 4, c = i & 15;
        h0[i] = embed[species[a] * 16 + c];
    }
}

// count-aware hs materialization: real slots only (~160K x 64 B = 10 MB)
__global__ void gather_hs(const int* __restrict__ snd, const int* __restrict__ cursor,
                          const float* __restrict__ h, float* __restrict__ edat) {
    int slot = blockIdx.x * blockDim.x + threadIdx.x;
    if (slot >= N_SLOTS) return;
    int a = slot / D_PAD, j = slot - a * D_PAD;
    int cnt = cursor[a] - a * D_PAD;
    if (cnt > D_PAD) cnt = D_PAD;
    if (j >= cnt) return;                     // pad hs already zeroed by pad_kernel
    int s = snd[slot];
    const float4* hp = (const float4*)(h + (size_t)s * 16);
    float4* ep = (float4*)(edat + (size_t)slot * EDW + 32);
    ep[0] = hp[0]; ep[1] = hp[1]; ep[2] = hp[2]; ep[3] = hp[3];
}

// transpose W_inv [256,16] -> W_invT [16,256] (both layers, one tiny launch)
__global__ void transpose_winv(const float* __restrict__ A, const float* __restrict__ B,
                               float* __restrict__ AT, float* __restrict__ BT) {
    int i = blockIdx.x * blockDim.x + threadIdx.x;
    if (i < 4096) {
        int k = i >> 4, c = i & 15;
        AT[c * 256 + k] = A[i];
    } else if (i < 8192) {
        int j = i - 4096;
        int k = j >> 4, c = j & 15;
        BT[c * 256 + k] = B[j];
    }
}

// ---------------- edge geometry -> slots ----------------

__global__ void edge_geom(const float* __restrict__ pos, const float* __restrict__ W_rad,
                          const int* __restrict__ senders, const int* __restrict__ receivers,
                          const int* __restrict__ perm,
                          float* __restrict__ edat, int* __restrict__ snd) {
    int e = blockIdx.x * blockDim.x + threadIdx.x;
    if (e >= N_EDGES) return;
    int s = senders[e], rc = receivers[e];
    int p = perm[e];
    float dx = pos[rc * 3 + 0] - pos[s * 3 + 0];
    float dy = pos[rc * 3 + 1] - pos[s * 3 + 1];
    float dz = pos[rc * 3 + 2] - pos[s * 3 + 2];
    float r = sqrtf(dx * dx + dy * dy + dz * dz);
    float rr = fmaxf(r, 1e-6f);
    float inv = 1.0f / rr;
    float x = dx * inv, y = dy * inv, z = dz * inv;
    float x2 = x * x, y2 = y * y, z2 = z * z;
    float she[16];
    she[0]  = 0.28209479f;
    she[1]  = 0.48860251f * y;
    she[2]  = 0.48860251f * z;
    she[3]  = 0.48860251f * x;
    she[4]  = 1.09254843f * x * y;
    she[5]  = 1.09254843f * y * z;
    she[6]  = 0.31539157f * (3.0f * z2 - 1.0f);
    she[7]  = 1.09254843f * x * z;
    she[8]  = 0.54627422f * (x2 - y2);
    she[9]  = 0.59004359f * y * (3.0f * x2 - y2);
    she[10] = 2.89061144f * x * y * z;
    she[11] = 0.45704579f * y * (5.0f * z2 - 1.0f);
    she[12] = 0.37317633f * z * (5.0f * z2 - 3.0f);
    she[13] = 0.45704579f * x * (5.0f * z2 - 1.0f);
    she[14] = 1.44530572f * z * (x2 - y2);
    she[15] = 0.59004359f * x * (x2 - 3.0f * y2);
    float* ed = edat + (size_t)p * EDW;
    ((float4*)ed)[0] = make_float4(she[0], she[1], she[2], she[3]);
    ((float4*)ed)[1] = make_float4(she[4], she[5], she[6], she[7]);
    ((float4*)ed)[2] = make_float4(she[8], she[9], she[10], she[11]);
    ((float4*)ed)[3] = make_float4(she[12], she[13], she[14], she[15]);
    float fc = 0.5f * (cosf(PI_F * fminf(r * 0.2f, 1.0f)) + 1.0f);
    const float c0 = 0.6324555320336759f; // sqrt(2/5)
    float bfv[8];
    #pragma unroll
    for (int n = 0; n < 8; ++n)
        bfv[n] = c0 * sinf((float)(n + 1) * PI_F * rr * 0.2f) * inv * fc;
    float Re[16];
    #pragma unroll
    for (int l = 0; l < 4; ++l) {
        #pragma unroll
        for (int n = 0; n < 4; ++n) {
            float acc = 0.0f;
            #pragma unroll
            for (int b = 0; b < 8; ++b) acc = fmaf(bfv[b], W_rad[l * 32 + b * 4 + n], acc);
            Re[l * 4 + n] = acc;
        }
    }
    ((float4*)ed)[4] = make_float4(Re[0], Re[1], Re[2], Re[3]);
    ((float4*)ed)[5] = make_float4(Re[4], Re[5], Re[6], Re[7]);
    ((float4*)ed)[6] = make_float4(Re[8], Re[9], Re[10], Re[11]);
    ((float4*)ed)[7] = make_float4(Re[12], Re[13], Re[14], Re[15]);
    snd[p] = s;
}

// ---------------- fused MP layer: wave-per-atom, register double-buffered ----------------
// Constant ~134us wall across R0-R7 regardless of structure; R6 showed the compiler
// re-serializes load batches (VGPR 44 when 54 were requested) -> effective MLP ~4.
// This version FORCES the in-flight window: two named register buffers, load(b+1)
// issued before consume(b), results live across the consume -- the compiler cannot
// fold them without violating dataflow. hs is re-materialized into the strip
// (gather_hs) so the hot loop is one contiguous stream of address-independent loads:
// no shfl, no indirection, no LDS in the load path. Per-wave epilogue, no barriers.

__global__ __launch_bounds__(256, 2) void mp_layer(
    const float* __restrict__ edat,
    const int* __restrict__ cursor,
    const float* __restrict__ W_invT,
    const float* __restrict__ cemb, float* __restrict__ h_out,
    const float* __restrict__ w_out, const float* __restrict__ comp_w,
    const int* __restrict__ species, const int* __restrict__ sids,
    float* __restrict__ accum, int do_energy)
{
    __shared__ __attribute__((aligned(16))) float lds[4][1088]; // per-wave scratch, 17408 B
    // per-wave region: s_A -> [0..1083] (m*68 + n*16 + c), inv overlay -> [0..255]

    const int t = threadIdx.x;
    const int w = t >> 6, lane = t & 63;
    const int atom = blockIdx.x * 4 + w;            // 2500*4 == 10000 exactly
    const int m = lane >> 2, cg = lane & 3;
    const int l = (m >= 9) ? 3 : (m >= 4) ? 2 : (m >= 1) ? 1 : 0;
    const int l4 = l * 4, cg4 = cg * 4;
    float* wl = &lds[w][0];

    int cnt = cursor[atom] - atom * D_PAD;
    if (cnt > D_PAD) cnt = D_PAD;
    const int nb = (cnt + B4 - 1) / B4;             // real 4-slot batches (pads zeroed)

    const float* strip = edat + (size_t)atom * (D_PAD * EDW);

    float acc[4][4];  // [n][j] ; A[m][n][c=cg*4+j]
    #pragma unroll
    for (int n = 0; n < 4; ++n)
        #pragma unroll
        for (int j = 0; j < 4; ++j) acc[n][j] = 0.f;

    // load a 4-slot batch into a named register buffer (12 independent loads)
    auto loadb = [&](int b, float* shb, float4* rvb, float4* hvb) {
        const float* bp = strip + b * (B4 * EDW);
        #pragma unroll
        for (int q = 0; q < B4; ++q) {
            const float* eq = bp + q * EDW;
            shb[q] = eq[m];
            rvb[q] = *(const float4*)(eq + 16 + l4);
            hvb[q] = *(const float4*)(eq + 32 + cg4);
        }
    };
    auto consume = [&](const float* shb, const float4* rvb, const float4* hvb) {
        #pragma unroll
        for (int q = 0; q < B4; ++q) {
            float hvj[4] = {hvb[q].x, hvb[q].y, hvb[q].z, hvb[q].w};
            float rvn[4] = {rvb[q].x, rvb[q].y, rvb[q].z, rvb[q].w};
            #pragma unroll
            for (int j = 0; j < 4; ++j) {
                float ww = shb[q] * hvj[j];
                #pragma unroll
                for (int n = 0; n < 4; ++n)
                    acc[n][j] = fmaf(ww, rvn[n], acc[n][j]);
            }
        }
    };

    if (nb > 0) {
        float  sh0[B4], sh1[B4];
        float4 rv0[B4], rv1[B4], hv0[B4], hv1[B4];
        loadb(0, sh0, rv0, hv0);
        int b = 0;
        for (;;) {
            if (b + 1 < nb) loadb(b + 1, sh1, rv1, hv1);   // in flight across consume
            consume(sh0, rv0, hv0);
            ++b; if (b >= nb) break;
            if (b + 1 < nb) loadb(b + 1, sh0, rv0, hv0);
            consume(sh1, rv1, hv1);
            ++b; if (b >= nb) break;
        }
    }

    // ---- per-wave epilogue (same-wave DS is in-order; no barriers) ----
    const float sc_l[4] = {1.0f, 0.57735026918962576f, 0.44721359549995794f, 0.37796447300922720f};
    #pragma unroll
    for (int n = 0; n < 4; ++n)
        *(float4*)&wl[m * 68 + n * 16 + cg4] =
            make_float4(acc[n][0], acc[n][1], acc[n][2], acc[n][3]);

    float inv4[4];
    #pragma unroll
    for (int i = 0; i < 4; ++i) {
        const int kt = lane * 4 + i;
        const int le = kt >> 6, k64 = kt & 63;
        const int m0 = le * le, m1 = m0 + 2 * le;
        float s = 0.f;
        for (int mm = m0; mm <= m1; ++mm) {
            float v = wl[mm * 68 + k64];
            s = fmaf(v, v, s);
        }
        inv4[i] = s * sc_l[le];
    }

    if (do_energy) {
        float s = 0.f;
        #pragma unroll
        for (int i = 0; i < 4; ++i) s = fmaf(inv4[i], w_out[lane * 4 + i], s);
        #pragma unroll
        for (int off = 32; off > 0; off >>= 1) s += __shfl_down(s, off);
        if (lane == 0) atomicAdd(&accum[sids[atom]], s + comp_w[species[atom]]);
    } else {
        // per-wave h_new = (inv @ W_inv) * cemb  (overlay aliases dead s_A region)
        *(float4*)&wl[lane * 4] = make_float4(inv4[0], inv4[1], inv4[2], inv4[3]);
        const int c = lane & 15, q4 = lane >> 4;
        const float* wrow = W_invT + c * 256 + q4 * 64;
        float p = 0.f;
        #pragma unroll
        for (int kk = 0; kk < 16; ++kk) {
            float4 iv = *(const float4*)&wl[q4 * 64 + kk * 4];
            float4 wv = *(const float4*)(wrow + kk * 4);
            p = fmaf(iv.x, wv.x, p);
            p = fmaf(iv.y, wv.y, p);
            p = fmaf(iv.z, wv.z, p);
            p = fmaf(iv.w, wv.w, p);
        }
        p += __shfl_xor(p, 16);
        p += __shfl_xor(p, 32);
        if (lane < 16) h_out[atom * 16 + c] = p * cemb[atom * 16 + c];
    }
}

__global__ void out_kernel(const float* __restrict__ accum, float* __restrict__ out) {
    int t = threadIdx.x;
    if (t < N_STRUCT) out[t] = accum[t];
}

// ---------------- launch ----------------

extern "C" void kernel_launch(void* const* d_in, const int* in_sizes, int n_in,
                              void* d_out, int out_size, void* d_ws, size_t ws_size,
                              hipStream_t stream) {
    const float* positions = (const float*)d_in[0];
    const float* embed     = (const float*)d_in[1];
    const float* W_rad     = (const float*)d_in[2];
    const float* W_inv1    = (const float*)d_in[3];
    const float* W_inv2    = (const float*)d_in[4];
    const float* w_out     = (const float*)d_in[5];
    const float* comp_w    = (const float*)d_in[6];
    const int* senders    = (const int*)d_in[7];
    const int* receivers  = (const int*)d_in[8];
    const int* species    = (const int*)d_in[9];
    const int* sids       = (const int*)d_in[10];
    float* out = (float*)d_out;

    char* ws = (char*)d_ws;
    size_t off = 0;
    auto alloc = [&](size_t bytes) -> void* {
        void* p = ws + off;
        off = (off + bytes + 255) & ~(size_t)255;
        return p;
    };
    float* edat     = (float*)alloc((size_t)N_SLOTS * EDW * 4);   // 92.2 MB
    float* h0       = (float*)alloc((size_t)N_ATOMS * 16 * 4);
    float* h1       = (float*)alloc((size_t)N_ATOMS * 16 * 4);
    int*   cursor   = (int*)alloc((size_t)N_ATOMS * 4);
    int*   perm     = (int*)alloc((size_t)N_EDGES * 4);
    int*   snd      = (int*)alloc((size_t)N_SLOTS * 4);
    float* accum    = (float*)alloc(8 * 4);
    float* WT1      = (float*)alloc(4096 * 4);
    float* WT2      = (float*)alloc(4096 * 4);

    const int EB = (N_EDGES + 255) / 256;            // 625
    const int HB = (N_ATOMS * 16 + 255) / 256;       // 625
    const int AB = (N_ATOMS + 255) / 256;            // 40
    const int PB = (N_ATOMS * 3 + 255) / 256;        // 118
    const int SB = (N_SLOTS + 255) / 256;            // 1875

    init_kernel<<<AB, 256, 0, stream>>>(cursor, accum);
    scatter_kernel<<<EB, 256, 0, stream>>>(receivers, cursor, perm);
    pad_kernel<<<PB, 256, 0, stream>>>(cursor, edat);
    edge_geom<<<EB, 256, 0, stream>>>(positions, W_rad, senders, receivers, perm,
                                      edat, snd);
    emb_kernel<<<HB, 256, 0, stream>>>(embed, species, h0);
    transpose_winv<<<32, 256, 0, stream>>>(W_inv1, W_inv2, WT1, WT2);

    // layer 1
    gather_hs<<<SB, 256, 0, stream>>>(snd, cursor, h0, edat);
    mp_layer<<<N_ATOMS / 4, 256, 0, stream>>>(edat, cursor, WT1, h0, h1,
                                              w_out, comp_w, species, sids, accum, 0);
    // layer 2 (energy)
    gather_hs<<<SB, 256, 0, stream>>>(snd, cursor, h1, edat);
    mp_layer<<<N_ATOMS / 4, 256, 0, stream>>>(edat, cursor, WT2, h0, h1,
                                              w_out, comp_w, species, sids, accum, 1);

    out_kernel<<<1, 64, 0, stream>>>(accum, out);
}

// Round 10
// 289.269 us; speedup vs baseline: 1.0083x; 1.0083x over previous
//
#include <hip/hip_runtime.h>

#define N_ATOMS 10000
#define N_EDGES 160000
#define N_STRUCT 8
#define D_PAD 48             // max slots per atom; P(Poisson(16) > 48) ~ 2e-7 overall
#define EDW 48               // floats per slot: [0..15]=sh, [16..31]=R, [32..47]=hs
#define N_SLOTS (N_ATOMS * D_PAD)
#define B4 4                 // slots per register batch (12 asm loads per batch)
#define PI_F 3.14159265358979323846f

typedef float v4f __attribute__((ext_vector_type(4)));

// ---- inline-asm loads: compiler cannot re-serialize these against vmcnt ----
#define LD1(dst, p, off) \
    asm volatile("global_load_dword %0, %1, off offset:" off \
                 : "=&v"(dst) : "v"(p) : "memory")
#define LD4(dst, p, off) \
    asm volatile("global_load_dwordx4 %0, %1, off offset:" off \
                 : "=&v"(dst) : "v"(p) : "memory")
#define VMCNT(n) do { \
    asm volatile("s_waitcnt vmcnt(" n ")" ::: "memory"); \
    __builtin_amdgcn_sched_barrier(0); \
} while (0)

// ---------------- setup ----------------

__global__ void init_kernel(int* __restrict__ cursor, float* __restrict__ accum) {
    int i = blockIdx.x * blockDim.x + threadIdx.x;
    if (i < N_ATOMS) cursor[i] = i * D_PAD;
    if (i < N_STRUCT) accum[i] = 0.f;
}

__global__ void scatter_kernel(const int* __restrict__ receivers, int* __restrict__ cursor,
                               int* __restrict__ perm) {
    int e = blockIdx.x * blockDim.x + threadIdx.x;
    if (e < N_EDGES) perm[e] = atomicAdd(&cursor[receivers[e]], 1);
}

// zero ONLY the pad slots [cnt, ceil4(cnt)) of each atom (all 48 floats)
__global__ void pad_kernel(const int* __restrict__ cursor, float* __restrict__ edat) {
    int i = blockIdx.x * blockDim.x + threadIdx.x;
    if (i >= N_ATOMS * 3) return;
    int a = i / 3, j = i % 3;
    int cnt = cursor[a] - a * D_PAD;
    if (cnt > D_PAD) cnt = D_PAD;
    int c4 = (cnt + B4 - 1) / B4 * B4;
    if (c4 > D_PAD) c4 = D_PAD;
    int slot = cnt + j;
    if (slot < c4) {
        float4 z = make_float4(0.f, 0.f, 0.f, 0.f);
        float4* p = (float4*)(edat + (size_t)(a * D_PAD + slot) * EDW);
        #pragma unroll
        for (int k = 0; k < 12; ++k) p[k] = z;
    }
}

__global__ void emb_kernel(const float* __restrict__ embed, const int* __restrict__ species,
                           float* __restrict__ h0) {
    int i = blockIdx.x * blockDim.x + threadIdx.x;
    if (i < N_ATOMS * 16) {
        int a = i >> 4, c = i & 15;
        h0[i] = embed[species[a] * 16 + c];
    }
}

// count-aware hs materialization: real slots only (~160K x 64 B = 10 MB)
__global__ void gather_hs(const int* __restrict__ snd, const int* __restrict__ cursor,
                          const float* __restrict__ h, float* __restrict__ edat) {
    int slot = blockIdx.x * blockDim.x + threadIdx.x;
    if (slot >= N_SLOTS) return;
    int a = slot / D_PAD, j = slot - a * D_PAD;
    int cnt = cursor[a] - a * D_PAD;
    if (cnt > D_PAD) cnt = D_PAD;
    if (j >= cnt) return;                     // pad hs already zeroed by pad_kernel
    int s = snd[slot];
    const float4* hp = (const float4*)(h + (size_t)s * 16);
    float4* ep = (float4*)(edat + (size_t)slot * EDW + 32);
    ep[0] = hp[0]; ep[1] = hp[1]; ep[2] = hp[2]; ep[3] = hp[3];
}

// transpose W_inv [256,16] -> W_invT [16,256] (both layers, one tiny launch)
__global__ void transpose_winv(const float* __restrict__ A, const float* __restrict__ B,
                               float* __restrict__ AT, float* __restrict__ BT) {
    int i = blockIdx.x * blockDim.x + threadIdx.x;
    if (i < 4096) {
        int k = i >> 4, c = i & 15;
        AT[c * 256 + k] = A[i];
    } else if (i < 8192) {
        int j = i - 4096;
        int k = j >> 4, c = j & 15;
        BT[c * 256 + k] = B[j];
    }
}

// ---------------- edge geometry -> slots ----------------

__global__ void edge_geom(const float* __restrict__ pos, const float* __restrict__ W_rad,
                          const int* __restrict__ senders, const int* __restrict__ receivers,
                          const int* __restrict__ perm,
                          float* __restrict__ edat, int* __restrict__ snd) {
    int e = blockIdx.x * blockDim.x + threadIdx.x;
    if (e >= N_EDGES) return;
    int s = senders[e], rc = receivers[e];
    int p = perm[e];
    float dx = pos[rc * 3 + 0] - pos[s * 3 + 0];
    float dy = pos[rc * 3 + 1] - pos[s * 3 + 1];
    float dz = pos[rc * 3 + 2] - pos[s * 3 + 2];
    float r = sqrtf(dx * dx + dy * dy + dz * dz);
    float rr = fmaxf(r, 1e-6f);
    float inv = 1.0f / rr;
    float x = dx * inv, y = dy * inv, z = dz * inv;
    float x2 = x * x, y2 = y * y, z2 = z * z;
    float she[16];
    she[0]  = 0.28209479f;
    she[1]  = 0.48860251f * y;
    she[2]  = 0.48860251f * z;
    she[3]  = 0.48860251f * x;
    she[4]  = 1.09254843f * x * y;
    she[5]  = 1.09254843f * y * z;
    she[6]  = 0.31539157f * (3.0f * z2 - 1.0f);
    she[7]  = 1.09254843f * x * z;
    she[8]  = 0.54627422f * (x2 - y2);
    she[9]  = 0.59004359f * y * (3.0f * x2 - y2);
    she[10] = 2.89061144f * x * y * z;
    she[11] = 0.45704579f * y * (5.0f * z2 - 1.0f);
    she[12] = 0.37317633f * z * (5.0f * z2 - 3.0f);
    she[13] = 0.45704579f * x * (5.0f * z2 - 1.0f);
    she[14] = 1.44530572f * z * (x2 - y2);
    she[15] = 0.59004359f * x * (x2 - 3.0f * y2);
    float* ed = edat + (size_t)p * EDW;
    ((float4*)ed)[0] = make_float4(she[0], she[1], she[2], she[3]);
    ((float4*)ed)[1] = make_float4(she[4], she[5], she[6], she[7]);
    ((float4*)ed)[2] = make_float4(she[8], she[9], she[10], she[11]);
    ((float4*)ed)[3] = make_float4(she[12], she[13], she[14], she[15]);
    float fc = 0.5f * (cosf(PI_F * fminf(r * 0.2f, 1.0f)) + 1.0f);
    const float c0 = 0.6324555320336759f; // sqrt(2/5)
    float bfv[8];
    #pragma unroll
    for (int n = 0; n < 8; ++n)
        bfv[n] = c0 * sinf((float)(n + 1) * PI_F * rr * 0.2f) * inv * fc;
    float Re[16];
    #pragma unroll
    for (int l = 0; l < 4; ++l) {
        #pragma unroll
        for (int n = 0; n < 4; ++n) {
            float acc = 0.0f;
            #pragma unroll
            for (int b = 0; b < 8; ++b) acc = fmaf(bfv[b], W_rad[l * 32 + b * 4 + n], acc);
            Re[l * 4 + n] = acc;
        }
    }
    ((float4*)ed)[4] = make_float4(Re[0], Re[1], Re[2], Re[3]);
    ((float4*)ed)[5] = make_float4(Re[4], Re[5], Re[6], Re[7]);
    ((float4*)ed)[6] = make_float4(Re[8], Re[9], Re[10], Re[11]);
    ((float4*)ed)[7] = make_float4(Re[12], Re[13], Re[14], Re[15]);
    snd[p] = s;
}

// ---------------- fused MP layer: wave-per-atom, ASM-forced MLP ----------------
// Nine rounds: mp_layer invariant at ~134us; back-computed in-flight memory is
// ~3-10 lines/CU => effective MLP~1/wave. Compiler provably vetoed every source-
// level batching attempt (VGPR 44-68 when the window needs ~100). This version
// issues each 4-slot batch as 12 inline-asm global loads (opaque to the
// scheduler), ping-pongs two named register buffer sets, and drains with counted
// s_waitcnt vmcnt(12) -- vmcnt(0) only at the tail. sched_barrier(0) after each
// wait per guide rule #18 (FMAs must not hoist above the wait).

// issue one 4-slot batch into buffer set S (12 loads, 768 B span per stream)
#define ISSUE(S) do { \
    LD1(S##_sh0, pa, "0");   LD1(S##_sh1, pa, "192"); \
    LD1(S##_sh2, pa, "384"); LD1(S##_sh3, pa, "576"); \
    LD4(S##_rv0, pb, "0");   LD4(S##_rv1, pb, "192"); \
    LD4(S##_rv2, pb, "384"); LD4(S##_rv3, pb, "576"); \
    LD4(S##_hv0, pc, "0");   LD4(S##_hv1, pc, "192"); \
    LD4(S##_hv2, pc, "384"); LD4(S##_hv3, pc, "576"); \
    pa += 192; pb += 192; pc += 192; \
} while (0)

#define CONS1(sh, rv, hv) do { \
    float ww0 = sh * hv[0], ww1 = sh * hv[1], ww2 = sh * hv[2], ww3 = sh * hv[3]; \
    acc[0][0] = fmaf(ww0, rv[0], acc[0][0]); acc[1][0] = fmaf(ww0, rv[1], acc[1][0]); \
    acc[2][0] = fmaf(ww0, rv[2], acc[2][0]); acc[3][0] = fmaf(ww0, rv[3], acc[3][0]); \
    acc[0][1] = fmaf(ww1, rv[0], acc[0][1]); acc[1][1] = fmaf(ww1, rv[1], acc[1][1]); \
    acc[2][1] = fmaf(ww1, rv[2], acc[2][1]); acc[3][1] = fmaf(ww1, rv[3], acc[3][1]); \
    acc[0][2] = fmaf(ww2, rv[0], acc[0][2]); acc[1][2] = fmaf(ww2, rv[1], acc[1][2]); \
    acc[2][2] = fmaf(ww2, rv[2], acc[2][2]); acc[3][2] = fmaf(ww2, rv[3], acc[3][2]); \
    acc[0][3] = fmaf(ww3, rv[0], acc[0][3]); acc[1][3] = fmaf(ww3, rv[1], acc[1][3]); \
    acc[2][3] = fmaf(ww3, rv[2], acc[2][3]); acc[3][3] = fmaf(ww3, rv[3], acc[3][3]); \
} while (0)

#define CONSUME(S) do { \
    CONS1(S##_sh0, S##_rv0, S##_hv0); \
    CONS1(S##_sh1, S##_rv1, S##_hv1); \
    CONS1(S##_sh2, S##_rv2, S##_hv2); \
    CONS1(S##_sh3, S##_rv3, S##_hv3); \
} while (0)

__global__ __launch_bounds__(256, 2) void mp_layer(
    const float* __restrict__ edat,
    const int* __restrict__ cursor,
    const float* __restrict__ W_invT,
    const float* __restrict__ cemb, float* __restrict__ h_out,
    const float* __restrict__ w_out, const float* __restrict__ comp_w,
    const int* __restrict__ species, const int* __restrict__ sids,
    float* __restrict__ accum, int do_energy)
{
    __shared__ __attribute__((aligned(16))) float lds[4][1088]; // per-wave scratch
    const int t = threadIdx.x;
    const int w = t >> 6, lane = t & 63;
    const int atom = blockIdx.x * 4 + w;            // 2500*4 == 10000 exactly
    const int m = lane >> 2, cg = lane & 3;
    const int l = (m >= 9) ? 3 : (m >= 4) ? 2 : (m >= 1) ? 1 : 0;
    const int l4 = l * 4, cg4 = cg * 4;
    float* wl = &lds[w][0];

    int cnt = cursor[atom] - atom * D_PAD;
    if (cnt > D_PAD) cnt = D_PAD;
    const int nb = (cnt + B4 - 1) / B4;             // real 4-slot batches (pads zeroed)

    const float* strip = edat + (size_t)atom * (D_PAD * EDW);

    float acc[4][4];
    #pragma unroll
    for (int n = 0; n < 4; ++n)
        #pragma unroll
        for (int j = 0; j < 4; ++j) acc[n][j] = 0.f;

    if (nb > 0) {
        const float* pa = strip + m;                // per-lane stream A: sh
        const float* pb = strip + 16 + l4;          // per-lane stream B: R
        const float* pc = strip + 32 + cg4;         // per-lane stream C: hs
        float A_sh0, A_sh1, A_sh2, A_sh3, B_sh0, B_sh1, B_sh2, B_sh3;
        v4f   A_rv0, A_rv1, A_rv2, A_rv3, B_rv0, B_rv1, B_rv2, B_rv3;
        v4f   A_hv0, A_hv1, A_hv2, A_hv3, B_hv0, B_hv1, B_hv2, B_hv3;

        ISSUE(A);
        int b = 0;
        for (;;) {
            if (b + 1 < nb) { ISSUE(B); VMCNT("12"); } else { VMCNT("0"); }
            CONSUME(A);
            ++b; if (b >= nb) break;
            if (b + 1 < nb) { ISSUE(A); VMCNT("12"); } else { VMCNT("0"); }
            CONSUME(B);
            ++b; if (b >= nb) break;
        }
    }

    // ---- per-wave epilogue (same-wave DS is in-order; no barriers) ----
    const float sc_l[4] = {1.0f, 0.57735026918962576f, 0.44721359549995794f, 0.37796447300922720f};
    #pragma unroll
    for (int n = 0; n < 4; ++n)
        *(float4*)&wl[m * 68 + n * 16 + cg4] =
            make_float4(acc[n][0], acc[n][1], acc[n][2], acc[n][3]);

    float inv4[4];
    #pragma unroll
    for (int i = 0; i < 4; ++i) {
        const int kt = lane * 4 + i;
        const int le = kt >> 6, k64 = kt & 63;
        const int m0 = le * le, m1 = m0 + 2 * le;
        float s = 0.f;
        for (int mm = m0; mm <= m1; ++mm) {
            float v = wl[mm * 68 + k64];
            s = fmaf(v, v, s);
        }
        inv4[i] = s * sc_l[le];
    }

    if (do_energy) {
        float s = 0.f;
        #pragma unroll
        for (int i = 0; i < 4; ++i) s = fmaf(inv4[i], w_out[lane * 4 + i], s);
        #pragma unroll
        for (int off = 32; off > 0; off >>= 1) s += __shfl_down(s, off);
        if (lane == 0) atomicAdd(&accum[sids[atom]], s + comp_w[species[atom]]);
    } else {
        // per-wave h_new = (inv @ W_inv) * cemb  (overlay aliases dead s_A region)
        *(float4*)&wl[lane * 4] = make_float4(inv4[0], inv4[1], inv4[2], inv4[3]);
        const int c = lane & 15, q4 = lane >> 4;
        const float* wrow = W_invT + c * 256 + q4 * 64;
        float p = 0.f;
        #pragma unroll
        for (int kk = 0; kk < 16; ++kk) {
            float4 iv = *(const float4*)&wl[q4 * 64 + kk * 4];
            float4 wv = *(const float4*)(wrow + kk * 4);
            p = fmaf(iv.x, wv.x, p);
            p = fmaf(iv.y, wv.y, p);
            p = fmaf(iv.z, wv.z, p);
            p = fmaf(iv.w, wv.w, p);
        }
        p += __shfl_xor(p, 16);
        p += __shfl_xor(p, 32);
        if (lane < 16) h_out[atom * 16 + c] = p * cemb[atom * 16 + c];
    }
}

__global__ void out_kernel(const float* __restrict__ accum, float* __restrict__ out) {
    int t = threadIdx.x;
    if (t < N_STRUCT) out[t] = accum[t];
}

// ---------------- launch ----------------

extern "C" void kernel_launch(void* const* d_in, const int* in_sizes, int n_in,
                              void* d_out, int out_size, void* d_ws, size_t ws_size,
                              hipStream_t stream) {
    const float* positions = (const float*)d_in[0];
    const float* embed     = (const float*)d_in[1];
    const float* W_rad     = (const float*)d_in[2];
    const float* W_inv1    = (const float*)d_in[3];
    const float* W_inv2    = (const float*)d_in[4];
    const float* w_out     = (const float*)d_in[5];
    const float* comp_w    = (const float*)d_in[6];
    const int* senders    = (const int*)d_in[7];
    const int* receivers  = (const int*)d_in[8];
    const int* species    = (const int*)d_in[9];
    const int* sids       = (const int*)d_in[10];
    float* out = (float*)d_out;

    char* ws = (char*)d_ws;
    size_t off = 0;
    auto alloc = [&](size_t bytes) -> void* {
        void* p = ws + off;
        off = (off + bytes + 255) & ~(size_t)255;
        return p;
    };
    float* edat     = (float*)alloc((size_t)N_SLOTS * EDW * 4);   // 92.2 MB
    float* h0       = (float*)alloc((size_t)N_ATOMS * 16 * 4);
    float* h1       = (float*)alloc((size_t)N_ATOMS * 16 * 4);
    int*   cursor   = (int*)alloc((size_t)N_ATOMS * 4);
    int*   perm     = (int*)alloc((size_t)N_EDGES * 4);
    int*   snd      = (int*)alloc((size_t)N_SLOTS * 4);
    float* accum    = (float*)alloc(8 * 4);
    float* WT1      = (float*)alloc(4096 * 4);
    float* WT2      = (float*)alloc(4096 * 4);

    const int EB = (N_EDGES + 255) / 256;            // 625
    const int HB = (N_ATOMS * 16 + 255) / 256;       // 625
    const int AB = (N_ATOMS + 255) / 256;            // 40
    const int PB = (N_ATOMS * 3 + 255) / 256;        // 118
    const int SB = (N_SLOTS + 255) / 256;            // 1875

    init_kernel<<<AB, 256, 0, stream>>>(cursor, accum);
    scatter_kernel<<<EB, 256, 0, stream>>>(receivers, cursor, perm);
    pad_kernel<<<PB, 256, 0, stream>>>(cursor, edat);
    edge_geom<<<EB, 256, 0, stream>>>(positions, W_rad, senders, receivers, perm,
                                      edat, snd);
    emb_kernel<<<HB, 256, 0, stream>>>(embed, species, h0);
    transpose_winv<<<32, 256, 0, stream>>>(W_inv1, W_inv2, WT1, WT2);

    // layer 1
    gather_hs<<<SB, 256, 0, stream>>>(snd, cursor, h0, edat);
    mp_layer<<<N_ATOMS / 4, 256, 0, stream>>>(edat, cursor, WT1, h0, h1,
                                              w_out, comp_w, species, sids, accum, 0);
    // layer 2 (energy)
    gather_hs<<<SB, 256, 0, stream>>>(snd, cursor, h1, edat);
    mp_layer<<<N_ATOMS / 4, 256, 0, stream>>>(edat, cursor, WT2, h0, h1,
                                              w_out, comp_w, species, sids, accum, 1);

    out_kernel<<<1, 64, 0, stream>>>(accum, out);
}